// Round 1
// baseline (356.226 us; speedup 1.0000x reference)
//
#include <hip/hip_runtime.h>
#include <math.h>

#define D 512
#define K 14
#define EPS 1e-8f

// Output float offsets (reference tuple order, flattened)
#define O_SNN       0          // 16*4096
#define O_PHINA     65536      // 16*4096*13
#define O_SAN       917504     // 16*4096
#define O_SAA       983040     // 16*4096
#define O_PHIOTHER  1048576    // 16*4096*12
#define O_SAANORM   1835008    // 16*4096
#define O_PSEUDO    1900544    // 16*4096
#define O_SCORES    1966080    // 16*4096
#define O_TN        2031616    // 512

__device__ __forceinline__ float wave_sum(float v) {
    v += __shfl_xor(v, 1);
    v += __shfl_xor(v, 2);
    v += __shfl_xor(v, 4);
    v += __shfl_xor(v, 8);
    v += __shfl_xor(v, 16);
    v += __shfl_xor(v, 32);
    return v;
}

__device__ __forceinline__ float wave_min(float v) {
    v = fminf(v, __shfl_xor(v, 1));
    v = fminf(v, __shfl_xor(v, 2));
    v = fminf(v, __shfl_xor(v, 4));
    v = fminf(v, __shfl_xor(v, 8));
    v = fminf(v, __shfl_xor(v, 16));
    v = fminf(v, __shfl_xor(v, 32));
    return v;
}
__device__ __forceinline__ float wave_max(float v) {
    v = fmaxf(v, __shfl_xor(v, 1));
    v = fmaxf(v, __shfl_xor(v, 2));
    v = fmaxf(v, __shfl_xor(v, 4));
    v = fmaxf(v, __shfl_xor(v, 8));
    v = fmaxf(v, __shfl_xor(v, 16));
    v = fmaxf(v, __shfl_xor(v, 32));
    return v;
}

// Kernel A: normalize T_emb rows 0..13 into W[0..13], copy w_score into W[14],
// and write T_n_enhanced (= normalized T_emb[13]) to output.
// 15 waves, one per row.
__global__ __launch_bounds__(960) void kprep(const float* __restrict__ T_emb,
                                             const float* __restrict__ w_score,
                                             float* __restrict__ W,
                                             float* __restrict__ tn_out) {
    int lane = threadIdx.x & 63;
    int w = threadIdx.x >> 6; // 0..14
    float4* W4 = (float4*)W;
    if (w < K) {
        const float4* src = (const float4*)T_emb + w * 128;
        float4 a = src[lane];
        float4 b = src[64 + lane];
        float ss = a.x * a.x + a.y * a.y + a.z * a.z + a.w * a.w
                 + b.x * b.x + b.y * b.y + b.z * b.z + b.w * b.w;
        ss = wave_sum(ss);
        float inv = 1.0f / (sqrtf(ss) + EPS);
        float4 na = make_float4(a.x * inv, a.y * inv, a.z * inv, a.w * inv);
        float4 nb = make_float4(b.x * inv, b.y * inv, b.z * inv, b.w * inv);
        W4[w * 128 + lane] = na;
        W4[w * 128 + 64 + lane] = nb;
        if (w == K - 1) {
            float4* t4 = (float4*)tn_out;
            t4[lane] = na;
            t4[64 + lane] = nb;
        }
    } else {
        const float4* src = (const float4*)w_score;
        W4[14 * 128 + lane] = src[lane];
        W4[14 * 128 + 64 + lane] = src[64 + lane];
    }
}

// Kernel B: normal feats. 14 dots/row -> phi_na (k=0..12) and S_nn (k=13).
__global__ __launch_bounds__(256) void knormal(const float4* __restrict__ feats,
                                               const float4* __restrict__ W4,
                                               float* __restrict__ S_nn,
                                               float* __restrict__ phi_na,
                                               int nrows) {
    int lane = threadIdx.x & 63;
    int wave = (blockIdx.x * 256 + threadIdx.x) >> 6;
    int nwaves = (gridDim.x * 256) >> 6;

    float4 t0[K], t1[K];
#pragma unroll
    for (int k = 0; k < K; k++) {
        t0[k] = W4[k * 128 + lane];
        t1[k] = W4[k * 128 + 64 + lane];
    }

    for (int row = wave; row < nrows; row += nwaves) {
        float4 f0 = feats[row * 128 + lane];
        float4 f1 = feats[row * 128 + 64 + lane];
        float acc[K];
#pragma unroll
        for (int k = 0; k < K; k++) {
            float a = f0.x * t0[k].x + f0.y * t0[k].y + f0.z * t0[k].z + f0.w * t0[k].w
                    + f1.x * t1[k].x + f1.y * t1[k].y + f1.z * t1[k].z + f1.w * t1[k].w;
            acc[k] = wave_sum(a);
        }
        // lane k (0..12) -> phi_na[row*13+k]; lane 13 -> S_nn[row]
        float val = acc[0];
#pragma unroll
        for (int k = 1; k < K; k++) val = (lane == k) ? acc[k] : val;
        if (lane < 14) {
            float* ptr = (lane < 13) ? (phi_na + row * 13 + lane) : (S_nn + row);
            *ptr = val;
        }
    }
}

// Kernel C: anomaly feats. 15 dots/row: k=0..12 anomaly classes, 13 = T_n, 14 = w_score.
__global__ __launch_bounds__(256) void kanom(const float4* __restrict__ feats,
                                             const float4* __restrict__ W4,
                                             const int* __restrict__ cls,
                                             const float* __restrict__ b_score,
                                             float* __restrict__ S_an,
                                             float* __restrict__ S_aa,
                                             float* __restrict__ phi_other,
                                             float* __restrict__ scores,
                                             int nrows) {
    const int NK = 15;
    int lane = threadIdx.x & 63;
    int wave = (blockIdx.x * 256 + threadIdx.x) >> 6;
    int nwaves = (gridDim.x * 256) >> 6;

    float4 t0[NK], t1[NK];
#pragma unroll
    for (int k = 0; k < NK; k++) {
        t0[k] = W4[k * 128 + lane];
        t1[k] = W4[k * 128 + 64 + lane];
    }
    float bsc = *b_score;

    for (int row = wave; row < nrows; row += nwaves) {
        int b = row >> 12;
        int ci = cls[b]; // wave-uniform
        float4 f0 = feats[row * 128 + lane];
        float4 f1 = feats[row * 128 + 64 + lane];
        float acc[NK];
#pragma unroll
        for (int k = 0; k < NK; k++) {
            float a = f0.x * t0[k].x + f0.y * t0[k].y + f0.z * t0[k].z + f0.w * t0[k].w
                    + f1.x * t1[k].x + f1.y * t1[k].y + f1.z * t1[k].z + f1.w * t1[k].w;
            acc[k] = wave_sum(a);
        }
        // lanes 0..11: phi_aa_other (k index = lane<ci ? lane : lane+1)
        // lane 12: S_an = acc[13]; lane 13: S_aa_true = acc[ci]; lane 14: scores
        int sel;
        if (lane < 12) sel = (lane < ci) ? lane : lane + 1;
        else if (lane == 13) sel = ci;
        else sel = 0;

        float val = acc[0];
#pragma unroll
        for (int k = 1; k < 13; k++) val = (sel == k) ? acc[k] : val;
        if (lane == 12) val = acc[13];
        if (lane == 14) val = 1.0f / (1.0f + expf(-(acc[14] + bsc)));

        if (lane < 15) {
            float* ptr;
            if (lane < 12)       ptr = phi_other + row * 12 + lane;
            else if (lane == 12) ptr = S_an + row;
            else if (lane == 13) ptr = S_aa + row;
            else                 ptr = scores + row;
            *ptr = val;
        }
    }
}

// Kernel D: per-batch min/max of S_aa_true and S_an. One block per batch.
__global__ __launch_bounds__(256) void kminmax(const float* __restrict__ S_aa,
                                               const float* __restrict__ S_an,
                                               float* __restrict__ mm) {
    int b = blockIdx.x;
    int t = threadIdx.x;
    int lane = t & 63, wid = t >> 6;
    const float* pa = S_aa + b * 4096;
    const float* pn = S_an + b * 4096;
    float mnA = 1e30f, mxA = -1e30f, mnN = 1e30f, mxN = -1e30f;
    for (int i = t; i < 4096; i += 256) {
        float a = pa[i];
        float n = pn[i];
        mnA = fminf(mnA, a); mxA = fmaxf(mxA, a);
        mnN = fminf(mnN, n); mxN = fmaxf(mxN, n);
    }
    mnA = wave_min(mnA); mxA = wave_max(mxA);
    mnN = wave_min(mnN); mxN = wave_max(mxN);
    __shared__ float red[4][4];
    if (lane == 0) {
        red[wid][0] = mnA; red[wid][1] = mxA;
        red[wid][2] = mnN; red[wid][3] = mxN;
    }
    __syncthreads();
    if (t == 0) {
        float a0 = red[0][0], a1 = red[0][1], a2 = red[0][2], a3 = red[0][3];
        for (int w = 1; w < 4; w++) {
            a0 = fminf(a0, red[w][0]); a1 = fmaxf(a1, red[w][1]);
            a2 = fminf(a2, red[w][2]); a3 = fmaxf(a3, red[w][3]);
        }
        mm[b * 4 + 0] = a0; mm[b * 4 + 1] = a1;
        mm[b * 4 + 2] = a2; mm[b * 4 + 3] = a3;
    }
}

// Kernel E: fuse -> S_aa_norm, pseudo_labels.
__global__ __launch_bounds__(256) void kfinal(const float* __restrict__ S_aa,
                                              const float* __restrict__ S_an,
                                              const float* __restrict__ mm,
                                              float* __restrict__ S_aa_norm,
                                              float* __restrict__ pseudo) {
    int i = blockIdx.x * 256 + threadIdx.x;
    if (i >= 65536) return;
    int b = i >> 12;
    float mnA = mm[b * 4 + 0], mxA = mm[b * 4 + 1];
    float mnN = mm[b * 4 + 2], mxN = mm[b * 4 + 3];
    float s_aa = (S_aa[i] - mnA) / (mxA - mnA + EPS);
    float s_an = (S_an[i] - mnN) / (mxN - mnN + EPS);
    float fused = 0.8f * s_aa + 0.2f * (1.0f - s_an);
    pseudo[i] = fused > 0.55f ? 1.0f : 0.0f;
    S_aa_norm[i] = s_aa;
}

extern "C" void kernel_launch(void* const* d_in, const int* in_sizes, int n_in,
                              void* d_out, int out_size, void* d_ws, size_t ws_size,
                              hipStream_t stream) {
    const float* normal_feats  = (const float*)d_in[0];
    const float* anomaly_feats = (const float*)d_in[1];
    const int*   cls           = (const int*)d_in[2];
    const float* T_emb         = (const float*)d_in[3];
    const float* w_score       = (const float*)d_in[4];
    const float* b_score       = (const float*)d_in[5];
    float* out = (float*)d_out;

    float* W  = (float*)d_ws;                 // 15*512 floats
    float* mm = (float*)d_ws + 15 * 512;      // 16*4 floats

    const int nrows = 16 * 4096;

    kprep<<<1, 960, 0, stream>>>(T_emb, w_score, W, out + O_TN);

    knormal<<<1024, 256, 0, stream>>>((const float4*)normal_feats, (const float4*)W,
                                      out + O_SNN, out + O_PHINA, nrows);

    kanom<<<1024, 256, 0, stream>>>((const float4*)anomaly_feats, (const float4*)W,
                                    cls, b_score,
                                    out + O_SAN, out + O_SAA, out + O_PHIOTHER,
                                    out + O_SCORES, nrows);

    kminmax<<<16, 256, 0, stream>>>(out + O_SAA, out + O_SAN, mm);

    kfinal<<<256, 256, 0, stream>>>(out + O_SAA, out + O_SAN, mm,
                                    out + O_SAANORM, out + O_PSEUDO);
}

// Round 2
// 324.252 us; speedup vs baseline: 1.0986x; 1.0986x over previous
//
#include <hip/hip_runtime.h>
#include <math.h>

#define D 512
#define K 14
#define EPS 1e-8f

// Output float offsets (reference tuple order, flattened)
#define O_SNN       0          // 16*4096
#define O_PHINA     65536      // 16*4096*13
#define O_SAN       917504     // 16*4096
#define O_SAA       983040     // 16*4096
#define O_PHIOTHER  1048576    // 16*4096*12
#define O_SAANORM   1835008    // 16*4096
#define O_PSEUDO    1900544    // 16*4096
#define O_SCORES    1966080    // 16*4096
#define O_TN        2031616    // 512

__device__ __forceinline__ float wave_sum(float v) {
    v += __shfl_xor(v, 1);
    v += __shfl_xor(v, 2);
    v += __shfl_xor(v, 4);
    v += __shfl_xor(v, 8);
    v += __shfl_xor(v, 16);
    v += __shfl_xor(v, 32);
    return v;
}
__device__ __forceinline__ float wave_min(float v) {
    v = fminf(v, __shfl_xor(v, 1));
    v = fminf(v, __shfl_xor(v, 2));
    v = fminf(v, __shfl_xor(v, 4));
    v = fminf(v, __shfl_xor(v, 8));
    v = fminf(v, __shfl_xor(v, 16));
    v = fminf(v, __shfl_xor(v, 32));
    return v;
}
__device__ __forceinline__ float wave_max(float v) {
    v = fmaxf(v, __shfl_xor(v, 1));
    v = fmaxf(v, __shfl_xor(v, 2));
    v = fmaxf(v, __shfl_xor(v, 4));
    v = fmaxf(v, __shfl_xor(v, 8));
    v = fmaxf(v, __shfl_xor(v, 16));
    v = fmaxf(v, __shfl_xor(v, 32));
    return v;
}

// Transpose-reduction: 16 per-lane accumulators -> full 64-lane sums.
// 17 shuffles total (vs 96 for 16 independent butterflies).
// Result: lane l holds the total of value bitrev4(l & 15).
__device__ __forceinline__ float multi_reduce16(float (&vals)[16], int lane) {
#pragma unroll
    for (int s = 0; s < 4; s++) {
        const int half = 8 >> s;          // 8,4,2,1
        const bool sel = (lane >> s) & 1;
#pragma unroll
        for (int i = 0; i < half; i++) {
            float lo = vals[i], hi = vals[i + half];
            float a = sel ? lo : hi;
            float b = __shfl_xor(a, 1 << s);
            vals[i] = sel ? (hi + b) : (lo + b);
        }
    }
    float v = vals[0];
    v += __shfl_xor(v, 16);
    v += __shfl_xor(v, 32);
    return v;
}

__device__ __forceinline__ int bitrev4(int x) {
    return ((x & 1) << 3) | ((x & 2) << 1) | ((x & 4) >> 1) | ((x & 8) >> 3);
}

// Kernel A: normalize T_emb rows 0..13 into W[0..13], copy w_score into W[14],
// and write T_n_enhanced (= normalized T_emb[13]) to output. 15 waves.
__global__ __launch_bounds__(960) void kprep(const float* __restrict__ T_emb,
                                             const float* __restrict__ w_score,
                                             float* __restrict__ W,
                                             float* __restrict__ tn_out) {
    int lane = threadIdx.x & 63;
    int w = threadIdx.x >> 6; // 0..14
    float4* W4 = (float4*)W;
    if (w < K) {
        const float4* src = (const float4*)T_emb + w * 128;
        float4 a = src[lane];
        float4 b = src[64 + lane];
        float ss = a.x * a.x + a.y * a.y + a.z * a.z + a.w * a.w
                 + b.x * b.x + b.y * b.y + b.z * b.z + b.w * b.w;
        ss = wave_sum(ss);
        float inv = 1.0f / (sqrtf(ss) + EPS);
        float4 na = make_float4(a.x * inv, a.y * inv, a.z * inv, a.w * inv);
        float4 nb = make_float4(b.x * inv, b.y * inv, b.z * inv, b.w * inv);
        W4[w * 128 + lane] = na;
        W4[w * 128 + 64 + lane] = nb;
        if (w == K - 1) {
            float4* t4 = (float4*)tn_out;
            t4[lane] = na;
            t4[64 + lane] = nb;
        }
    } else {
        const float4* src = (const float4*)w_score;
        W4[14 * 128 + lane] = src[lane];
        W4[14 * 128 + 64 + lane] = src[64 + lane];
    }
}

// Kernel B: normal feats. Values 0..12 -> phi_na, 13 -> S_nn; 14,15 dummy.
__global__ __launch_bounds__(256, 2) void knormal(const float4* __restrict__ feats,
                                                  const float4* __restrict__ W4,
                                                  float* __restrict__ S_nn,
                                                  float* __restrict__ phi_na,
                                                  int nrows) {
    int lane = threadIdx.x & 63;
    int wave = (blockIdx.x * 256 + threadIdx.x) >> 6;
    int nwaves = (gridDim.x * 256) >> 6;

    float4 t0[K], t1[K];
#pragma unroll
    for (int k = 0; k < K; k++) {
        t0[k] = W4[k * 128 + lane];
        t1[k] = W4[k * 128 + 64 + lane];
    }
    const int myk = bitrev4(lane); // value index this lane ends up with (lane<16)

    int row = wave;
    float4 f0 = feats[row * 128 + lane];
    float4 f1 = feats[row * 128 + 64 + lane];
    while (row < nrows) {
        int nrow = row + nwaves;
        float4 g0, g1;
        if (nrow < nrows) {
            g0 = feats[nrow * 128 + lane];
            g1 = feats[nrow * 128 + 64 + lane];
        }
        float vals[16];
#pragma unroll
        for (int k = 0; k < K; k++) {
            vals[k] = f0.x * t0[k].x + f0.y * t0[k].y + f0.z * t0[k].z + f0.w * t0[k].w
                    + f1.x * t1[k].x + f1.y * t1[k].y + f1.z * t1[k].z + f1.w * t1[k].w;
        }
        vals[14] = 0.0f; vals[15] = 0.0f;
        float v = multi_reduce16(vals, lane);
        if (lane < 16 && myk < 14) {
            float* ptr = (myk < 13) ? (phi_na + row * 13 + myk) : (S_nn + row);
            *ptr = v;
        }
        row = nrow; f0 = g0; f1 = g1;
    }
}

// Kernel C: anomaly feats. Values 0..12 anomaly classes, 13 = T_n, 14 = w_score.
__global__ __launch_bounds__(256, 2) void kanom(const float4* __restrict__ feats,
                                                const float4* __restrict__ W4,
                                                const int* __restrict__ cls,
                                                const float* __restrict__ b_score,
                                                float* __restrict__ S_an,
                                                float* __restrict__ S_aa,
                                                float* __restrict__ phi_other,
                                                float* __restrict__ scores,
                                                int nrows) {
    const int NK = 15;
    int lane = threadIdx.x & 63;
    int wave = (blockIdx.x * 256 + threadIdx.x) >> 6;
    int nwaves = (gridDim.x * 256) >> 6;

    float4 t0[NK], t1[NK];
#pragma unroll
    for (int k = 0; k < NK; k++) {
        t0[k] = W4[k * 128 + lane];
        t1[k] = W4[k * 128 + 64 + lane];
    }
    float bsc = *b_score;
    const int myk = bitrev4(lane);

    int row = wave;
    float4 f0 = feats[row * 128 + lane];
    float4 f1 = feats[row * 128 + 64 + lane];
    while (row < nrows) {
        int nrow = row + nwaves;
        float4 g0, g1;
        if (nrow < nrows) {
            g0 = feats[nrow * 128 + lane];
            g1 = feats[nrow * 128 + 64 + lane];
        }
        int ci = cls[row >> 12]; // wave-uniform
        float vals[16];
#pragma unroll
        for (int k = 0; k < NK; k++) {
            vals[k] = f0.x * t0[k].x + f0.y * t0[k].y + f0.z * t0[k].z + f0.w * t0[k].w
                    + f1.x * t1[k].x + f1.y * t1[k].y + f1.z * t1[k].z + f1.w * t1[k].w;
        }
        vals[15] = 0.0f;
        float v = multi_reduce16(vals, lane);
        if (lane < 16 && myk < 15) {
            float* ptr;
            float val = v;
            if (myk < 13) {
                if (myk == ci) ptr = S_aa + row;
                else           ptr = phi_other + row * 12 + ((myk < ci) ? myk : myk - 1);
            } else if (myk == 13) {
                ptr = S_an + row;
            } else {
                ptr = scores + row;
                val = 1.0f / (1.0f + expf(-(v + bsc)));
            }
            *ptr = val;
        }
        row = nrow; f0 = g0; f1 = g1;
    }
}

// Kernel D: per-batch min/max of S_aa_true and S_an. One block per batch.
__global__ __launch_bounds__(256) void kminmax(const float* __restrict__ S_aa,
                                               const float* __restrict__ S_an,
                                               float* __restrict__ mm) {
    int b = blockIdx.x;
    int t = threadIdx.x;
    int lane = t & 63, wid = t >> 6;
    const float* pa = S_aa + b * 4096;
    const float* pn = S_an + b * 4096;
    float mnA = 1e30f, mxA = -1e30f, mnN = 1e30f, mxN = -1e30f;
    for (int i = t; i < 4096; i += 256) {
        float a = pa[i];
        float n = pn[i];
        mnA = fminf(mnA, a); mxA = fmaxf(mxA, a);
        mnN = fminf(mnN, n); mxN = fmaxf(mxN, n);
    }
    mnA = wave_min(mnA); mxA = wave_max(mxA);
    mnN = wave_min(mnN); mxN = wave_max(mxN);
    __shared__ float red[4][4];
    if (lane == 0) {
        red[wid][0] = mnA; red[wid][1] = mxA;
        red[wid][2] = mnN; red[wid][3] = mxN;
    }
    __syncthreads();
    if (t == 0) {
        float a0 = red[0][0], a1 = red[0][1], a2 = red[0][2], a3 = red[0][3];
        for (int w = 1; w < 4; w++) {
            a0 = fminf(a0, red[w][0]); a1 = fmaxf(a1, red[w][1]);
            a2 = fminf(a2, red[w][2]); a3 = fmaxf(a3, red[w][3]);
        }
        mm[b * 4 + 0] = a0; mm[b * 4 + 1] = a1;
        mm[b * 4 + 2] = a2; mm[b * 4 + 3] = a3;
    }
}

// Kernel E: fuse -> S_aa_norm, pseudo_labels.
__global__ __launch_bounds__(256) void kfinal(const float* __restrict__ S_aa,
                                              const float* __restrict__ S_an,
                                              const float* __restrict__ mm,
                                              float* __restrict__ S_aa_norm,
                                              float* __restrict__ pseudo) {
    int i = blockIdx.x * 256 + threadIdx.x;
    if (i >= 65536) return;
    int b = i >> 12;
    float mnA = mm[b * 4 + 0], mxA = mm[b * 4 + 1];
    float mnN = mm[b * 4 + 2], mxN = mm[b * 4 + 3];
    float s_aa = (S_aa[i] - mnA) / (mxA - mnA + EPS);
    float s_an = (S_an[i] - mnN) / (mxN - mnN + EPS);
    float fused = 0.8f * s_aa + 0.2f * (1.0f - s_an);
    pseudo[i] = fused > 0.55f ? 1.0f : 0.0f;
    S_aa_norm[i] = s_aa;
}

extern "C" void kernel_launch(void* const* d_in, const int* in_sizes, int n_in,
                              void* d_out, int out_size, void* d_ws, size_t ws_size,
                              hipStream_t stream) {
    const float* normal_feats  = (const float*)d_in[0];
    const float* anomaly_feats = (const float*)d_in[1];
    const int*   cls           = (const int*)d_in[2];
    const float* T_emb         = (const float*)d_in[3];
    const float* w_score       = (const float*)d_in[4];
    const float* b_score       = (const float*)d_in[5];
    float* out = (float*)d_out;

    float* W  = (float*)d_ws;                 // 15*512 floats
    float* mm = (float*)d_ws + 15 * 512;      // 16*4 floats

    const int nrows = 16 * 4096;

    kprep<<<1, 960, 0, stream>>>(T_emb, w_score, W, out + O_TN);

    knormal<<<1024, 256, 0, stream>>>((const float4*)normal_feats, (const float4*)W,
                                      out + O_SNN, out + O_PHINA, nrows);

    kanom<<<1024, 256, 0, stream>>>((const float4*)anomaly_feats, (const float4*)W,
                                    cls, b_score,
                                    out + O_SAN, out + O_SAA, out + O_PHIOTHER,
                                    out + O_SCORES, nrows);

    kminmax<<<16, 256, 0, stream>>>(out + O_SAA, out + O_SAN, mm);

    kfinal<<<256, 256, 0, stream>>>(out + O_SAA, out + O_SAN, mm,
                                    out + O_SAANORM, out + O_PSEUDO);
}